// Round 20
// baseline (15822.107 us; speedup 1.0000x reference)
//
#include <hip/hip_runtime.h>

#define S_LEN 1024
#define B_DIM 64
#define H_DIM 512
#define Y_SZ ((size_t)S_LEN * B_DIM * H_DIM)   // 33,554,432 elements

// ---------------------------------------------------------------------------
// GEMM (r13 structure, A-reads widened b32->b64): C[m,n] = sum_k A[m,k]*W[n,k]
// + bias[n]. Plain fp32 (exotic datapaths all fail on this toolchain).
// Design-space map (LDS cyc/wave-kt, VGPR, occ, µs):
//   r13 4x16: 1139, 64, 39% -> 494 (saturates LDS pipe = its floor)
//   r18 8x8 : 768, 68, 23% -> 565 (occupancy cliff, pipe 59% util)
//   r19 gA  : 480, 76, 23% -> 655 (VMEM latency exposed)
// => must cut LDS cycles INSIDE the 64-VGPR class. This kernel: A read as
// float2 (32 ds_read_b64 = 256 cyc vs 64 b32 = 371) -> 1024 cyc/wave-kt.
// __launch_bounds__(512, 8) pins the allocator to the 64-VGPR class.
// Same staging, 2 barriers/kt, conflict-free B split {cg*4+jj*128}. Block
// owns 64 rows exclusively; all C stores after last barrier -> in-place safe.
// Per-element k-accumulation order identical to r13 -> bit-identical output.
// ---------------------------------------------------------------------------
__global__ __launch_bounds__(512, 8) void gemm_valu(
    const float* A, const float* __restrict__ W,
    const float* __restrict__ bias, float* C) {
  __shared__ float Bl[16][512];  // [k][n], staged transposed
  __shared__ float Al[64][16];   // [r][k]

  const int tid = threadIdx.x;
  const int rg = tid >> 5;   // 0..15 (4 rows each)
  const int cg = tid & 31;   // 0..31 (16 cols: cg*4 + jj*128)
  const int brow = blockIdx.x * 64;

  float acc[4][16];
#pragma unroll
  for (int i = 0; i < 4; ++i)
#pragma unroll
    for (int j = 0; j < 16; ++j) acc[i][j] = 0.0f;

  for (int kt = 0; kt < 32; ++kt) {
    {
      const float* wp = W + (size_t)tid * 512 + kt * 16;
      float4 w0 = *(const float4*)(wp + 0);
      float4 w1 = *(const float4*)(wp + 4);
      float4 w2 = *(const float4*)(wp + 8);
      float4 w3 = *(const float4*)(wp + 12);
      Bl[0][tid] = w0.x;  Bl[1][tid] = w0.y;  Bl[2][tid] = w0.z;  Bl[3][tid] = w0.w;
      Bl[4][tid] = w1.x;  Bl[5][tid] = w1.y;  Bl[6][tid] = w1.z;  Bl[7][tid] = w1.w;
      Bl[8][tid] = w2.x;  Bl[9][tid] = w2.y;  Bl[10][tid] = w2.z; Bl[11][tid] = w2.w;
      Bl[12][tid] = w3.x; Bl[13][tid] = w3.y; Bl[14][tid] = w3.z; Bl[15][tid] = w3.w;
    }
    {
      const int r = tid >> 3, kk = (tid & 7) * 2;
      const float* ap = A + (size_t)(brow + r) * 512 + kt * 16 + kk;
      Al[r][kk] = ap[0];
      Al[r][kk + 1] = ap[1];
    }
    __syncthreads();
#pragma unroll
    for (int kp = 0; kp < 8; ++kp) {
      // A as b64 (float2): 4 reads per k-pair instead of 8 scalar reads
      float2 a0p = *(const float2*)&Al[rg * 4 + 0][kp * 2];
      float2 a1p = *(const float2*)&Al[rg * 4 + 1][kp * 2];
      float2 a2p = *(const float2*)&Al[rg * 4 + 2][kp * 2];
      float2 a3p = *(const float2*)&Al[rg * 4 + 3][kp * 2];
#define KSTEP(KIDX, CMP)                                                      \
      {                                                                       \
        const float a0 = a0p.CMP, a1 = a1p.CMP, a2 = a2p.CMP, a3 = a3p.CMP;   \
        _Pragma("unroll")                                                     \
        for (int jj = 0; jj < 4; ++jj) {                                      \
          float4 b = *(const float4*)&Bl[KIDX][cg * 4 + jj * 128];            \
          acc[0][jj * 4 + 0] += a0 * b.x; acc[0][jj * 4 + 1] += a0 * b.y;     \
          acc[0][jj * 4 + 2] += a0 * b.z; acc[0][jj * 4 + 3] += a0 * b.w;     \
          acc[1][jj * 4 + 0] += a1 * b.x; acc[1][jj * 4 + 1] += a1 * b.y;     \
          acc[1][jj * 4 + 2] += a1 * b.z; acc[1][jj * 4 + 3] += a1 * b.w;     \
          acc[2][jj * 4 + 0] += a2 * b.x; acc[2][jj * 4 + 1] += a2 * b.y;     \
          acc[2][jj * 4 + 2] += a2 * b.z; acc[2][jj * 4 + 3] += a2 * b.w;     \
          acc[3][jj * 4 + 0] += a3 * b.x; acc[3][jj * 4 + 1] += a3 * b.y;     \
          acc[3][jj * 4 + 2] += a3 * b.z; acc[3][jj * 4 + 3] += a3 * b.w;     \
        }                                                                     \
      }
      KSTEP(kp * 2, x)
      KSTEP(kp * 2 + 1, y)
#undef KSTEP
    }
    __syncthreads();
  }

#pragma unroll
  for (int i = 0; i < 4; ++i) {
    const int row = brow + rg * 4 + i;
#pragma unroll
    for (int jj = 0; jj < 4; ++jj) {
      const int c0 = cg * 4 + jj * 128;
      float4 o;
      o.x = acc[i][jj * 4 + 0] + bias[c0 + 0];
      o.y = acc[i][jj * 4 + 1] + bias[c0 + 1];
      o.z = acc[i][jj * 4 + 2] + bias[c0 + 2];
      o.w = acc[i][jj * 4 + 3] + bias[c0 + 3];
      *(float4*)&C[(size_t)row * 512 + c0] = o;
    }
  }
}

// ---------------------------------------------------------------------------
// DPP wave64 sum-reduce helper (r14 EXACT, hardware-proven).
// ---------------------------------------------------------------------------
__device__ static inline float dpp_add_step(float v, const int ctrl) {
  int perm;
  switch (ctrl) {  // ctrl is compile-time constant at each call site
    case 0xB1:  perm = __builtin_amdgcn_update_dpp(0, __builtin_bit_cast(int, v), 0xB1,  0xF, 0xF, true); break;
    case 0x4E:  perm = __builtin_amdgcn_update_dpp(0, __builtin_bit_cast(int, v), 0x4E,  0xF, 0xF, true); break;
    case 0x141: perm = __builtin_amdgcn_update_dpp(0, __builtin_bit_cast(int, v), 0x141, 0xF, 0xF, true); break;
    case 0x140: perm = __builtin_amdgcn_update_dpp(0, __builtin_bit_cast(int, v), 0x140, 0xF, 0xF, true); break;
    case 0x142: perm = __builtin_amdgcn_update_dpp(0, __builtin_bit_cast(int, v), 0x142, 0xF, 0xF, true); break;
    default:    perm = __builtin_amdgcn_update_dpp(0, __builtin_bit_cast(int, v), 0x143, 0xF, 0xF, true); break;
  }
  return v + __builtin_bit_cast(float, perm);
}

// ---------------------------------------------------------------------------
// Scan (r14 EXACT, hardware-proven ~174 µs): depth-8 prefetch ring, one wave
// per batch row, DPP reduction, relu6, in-place safe.
// ---------------------------------------------------------------------------
__global__ __launch_bounds__(64) void scan_ln_relu6(
    const float* lin, const float* __restrict__ rec,
    const float* __restrict__ gam, const float* __restrict__ bet,
    float* y, float* __restrict__ hlast) {
  const int b = blockIdx.x;
  const int lane = threadIdx.x;
  const int e0 = lane * 8;

  float rf[8], gf[8], bp[8], h[8];
#pragma unroll
  for (int i = 0; i < 8; ++i) {
    rf[i] = rec[e0 + i];
    gf[i] = gam[e0 + i];
    bp[i] = bet[e0 + i];
    h[i] = 0.0f;
  }

  const size_t BH = (size_t)B_DIM * H_DIM;
  const size_t base = (size_t)b * H_DIM + e0;

  float4 pa[8], pb[8];  // prefetch ring: row s0+k held in pa[k]/pb[k]
#pragma unroll
  for (int k = 0; k < 8; ++k) {
    pa[k] = *(const float4*)&lin[base + (size_t)k * BH];
    pb[k] = *(const float4*)&lin[base + (size_t)k * BH + 4];
  }

  for (int s0 = 0; s0 < S_LEN; s0 += 8) {
#pragma unroll
    for (int k = 0; k < 8; ++k) {   // k compile-time after unroll
      const int s = s0 + k;
      float hv[8];
      hv[0] = pa[k].x + rf[0] * h[0]; hv[1] = pa[k].y + rf[1] * h[1];
      hv[2] = pa[k].z + rf[2] * h[2]; hv[3] = pa[k].w + rf[3] * h[3];
      hv[4] = pb[k].x + rf[4] * h[4]; hv[5] = pb[k].y + rf[5] * h[5];
      hv[6] = pb[k].z + rf[6] * h[6]; hv[7] = pb[k].w + rf[7] * h[7];
      if (s + 8 < S_LEN) {  // issue prefetch for s+8 (consumed 8 steps later)
        pa[k] = *(const float4*)&lin[base + (size_t)(s + 8) * BH];
        pb[k] = *(const float4*)&lin[base + (size_t)(s + 8) * BH + 4];
      }
      float s1 = 0.0f, s2 = 0.0f;
#pragma unroll
      for (int i = 0; i < 8; ++i) {
        s1 += hv[i];
        s2 += hv[i] * hv[i];
      }
      // --- interleaved DPP butterfly: full 64-lane sums of s1, s2 ---
      s1 = dpp_add_step(s1, 0xB1);  s2 = dpp_add_step(s2, 0xB1);   // quad xor1
      s1 = dpp_add_step(s1, 0x4E);  s2 = dpp_add_step(s2, 0x4E);   // quad xor2
      s1 = dpp_add_step(s1, 0x141); s2 = dpp_add_step(s2, 0x141);  // half_mirror
      s1 = dpp_add_step(s1, 0x140); s2 = dpp_add_step(s2, 0x140);  // row_mirror
      s1 = dpp_add_step(s1, 0x142); s2 = dpp_add_step(s2, 0x142);  // bcast15
      s1 = dpp_add_step(s1, 0x143); s2 = dpp_add_step(s2, 0x143);  // bcast31
      const float S1 = __builtin_bit_cast(float,
          __builtin_amdgcn_readlane(__builtin_bit_cast(int, s1), 63));
      const float S2 = __builtin_bit_cast(float,
          __builtin_amdgcn_readlane(__builtin_bit_cast(int, s2), 63));
      const float mu = S1 * (1.0f / 512.0f);
      const float var = S2 * (1.0f / 512.0f) - mu * mu;  // biased variance
      const float rs = rsqrtf(var + 1e-6f);
      float4 o0, o1;
      float v;
      v = (hv[0] - mu) * rs * gf[0] + bp[0]; v = fminf(fmaxf(v, 0.0f), 6.0f); h[0] = v; o0.x = v;
      v = (hv[1] - mu) * rs * gf[1] + bp[1]; v = fminf(fmaxf(v, 0.0f), 6.0f); h[1] = v; o0.y = v;
      v = (hv[2] - mu) * rs * gf[2] + bp[2]; v = fminf(fmaxf(v, 0.0f), 6.0f); h[2] = v; o0.z = v;
      v = (hv[3] - mu) * rs * gf[3] + bp[3]; v = fminf(fmaxf(v, 0.0f), 6.0f); h[3] = v; o0.w = v;
      v = (hv[4] - mu) * rs * gf[4] + bp[4]; v = fminf(fmaxf(v, 0.0f), 6.0f); h[4] = v; o1.x = v;
      v = (hv[5] - mu) * rs * gf[5] + bp[5]; v = fminf(fmaxf(v, 0.0f), 6.0f); h[5] = v; o1.y = v;
      v = (hv[6] - mu) * rs * gf[6] + bp[6]; v = fminf(fmaxf(v, 0.0f), 6.0f); h[6] = v; o1.z = v;
      v = (hv[7] - mu) * rs * gf[7] + bp[7]; v = fminf(fmaxf(v, 0.0f), 6.0f); h[7] = v; o1.w = v;
      float* yp = y + base + (size_t)s * BH;
      *(float4*)yp = o0;
      *(float4*)(yp + 4) = o1;
    }
  }

  float* hp = hlast + b * 1024 + e0;
  float4 h0; h0.x = h[0]; h0.y = h[1]; h0.z = h[2]; h0.w = h[3];
  float4 h1; h1.x = h[4]; h1.y = h[5]; h1.z = h[6]; h1.w = h[7];
  *(float4*)hp = h0;
  *(float4*)(hp + 4) = h1;
}

extern "C" void kernel_launch(void* const* d_in, const int* in_sizes, int n_in,
                              void* d_out, int out_size, void* d_ws, size_t ws_size,
                              hipStream_t stream) {
  const float* x   = (const float*)d_in[0];
  const float* W0  = (const float*)d_in[1];
  const float* b0  = (const float*)d_in[2];
  const float* r0  = (const float*)d_in[3];
  const float* g0  = (const float*)d_in[4];
  const float* be0 = (const float*)d_in[5];
  const float* W1  = (const float*)d_in[6];
  const float* b1  = (const float*)d_in[7];
  const float* r1  = (const float*)d_in[8];
  const float* g1  = (const float*)d_in[9];
  const float* be1 = (const float*)d_in[10];

  float* out = (float*)d_out;
  float* R   = out;              // y-region: lin0 -> y0 -> lin1 -> y, in place
  float* hl0 = out + Y_SZ;       // hiddens flat: out[Y_SZ + b*1024 + l*512 + h]
  float* hl1 = out + Y_SZ + 512;
  (void)d_ws; (void)ws_size; (void)in_sizes; (void)n_in; (void)out_size;

  // layer 0
  gemm_valu<<<1024, 512, 0, stream>>>(x, W0, b0, R);
  scan_ln_relu6<<<64, 64, 0, stream>>>(R, r0, g0, be0, R, hl0);
  // layer 1 (reads y0 from R, writes lin1 over R; in-place-safe by design)
  gemm_valu<<<1024, 512, 0, stream>>>(R, W1, b1, R);
  scan_ln_relu6<<<64, 64, 0, stream>>>(R, r1, g1, be1, R, hl1);
}

// Round 21
// 1383.729 us; speedup vs baseline: 11.4344x; 11.4344x over previous
//
#include <hip/hip_runtime.h>

#define S_LEN 1024
#define B_DIM 64
#define H_DIM 512
#define Y_SZ ((size_t)S_LEN * B_DIM * H_DIM)   // 33,554,432 elements

// ---------------------------------------------------------------------------
// GEMM (r13 EXACT, hardware-proven 494 µs, 64 VGPR @ 39% occ — saturates the
// LDS pipe at its 1139 cyc/wave-kt floor; every tile/pin variant regressed:
// r12 68VGPR=570, r17 confl=606, r18 8x8=565, r19 globalA=655, r20 pin=8300).
// NO __launch_bounds__ min-waves pin — r20 proved it forces 32 VGPR + spills.
// Block owns 64 rows exclusively; all C stores after the last staging
// barrier -> in-place safe (C may alias A).
// ---------------------------------------------------------------------------
__global__ __launch_bounds__(512) void gemm_valu(
    const float* A, const float* __restrict__ W,
    const float* __restrict__ bias, float* C) {
  __shared__ float Bl[16][512];  // [k][n], staged transposed
  __shared__ float Al[64][16];   // [r][k]

  const int tid = threadIdx.x;
  const int rg = tid >> 5;   // 0..15 (4 rows each)
  const int cg = tid & 31;   // 0..31 (16 cols: cg*4 + jj*128)
  const int brow = blockIdx.x * 64;

  float acc[4][16];
#pragma unroll
  for (int i = 0; i < 4; ++i)
#pragma unroll
    for (int j = 0; j < 16; ++j) acc[i][j] = 0.0f;

  for (int kt = 0; kt < 32; ++kt) {
    {
      const float* wp = W + (size_t)tid * 512 + kt * 16;
      float4 w0 = *(const float4*)(wp + 0);
      float4 w1 = *(const float4*)(wp + 4);
      float4 w2 = *(const float4*)(wp + 8);
      float4 w3 = *(const float4*)(wp + 12);
      Bl[0][tid] = w0.x;  Bl[1][tid] = w0.y;  Bl[2][tid] = w0.z;  Bl[3][tid] = w0.w;
      Bl[4][tid] = w1.x;  Bl[5][tid] = w1.y;  Bl[6][tid] = w1.z;  Bl[7][tid] = w1.w;
      Bl[8][tid] = w2.x;  Bl[9][tid] = w2.y;  Bl[10][tid] = w2.z; Bl[11][tid] = w2.w;
      Bl[12][tid] = w3.x; Bl[13][tid] = w3.y; Bl[14][tid] = w3.z; Bl[15][tid] = w3.w;
    }
    {
      const int r = tid >> 3, kk = (tid & 7) * 2;
      const float* ap = A + (size_t)(brow + r) * 512 + kt * 16 + kk;
      Al[r][kk] = ap[0];
      Al[r][kk + 1] = ap[1];
    }
    __syncthreads();
#pragma unroll
    for (int k = 0; k < 16; ++k) {
      const float a0 = Al[rg * 4 + 0][k];
      const float a1 = Al[rg * 4 + 1][k];
      const float a2 = Al[rg * 4 + 2][k];
      const float a3 = Al[rg * 4 + 3][k];
#pragma unroll
      for (int jj = 0; jj < 4; ++jj) {
        float4 b = *(const float4*)&Bl[k][cg * 4 + jj * 128];
        acc[0][jj * 4 + 0] += a0 * b.x; acc[0][jj * 4 + 1] += a0 * b.y;
        acc[0][jj * 4 + 2] += a0 * b.z; acc[0][jj * 4 + 3] += a0 * b.w;
        acc[1][jj * 4 + 0] += a1 * b.x; acc[1][jj * 4 + 1] += a1 * b.y;
        acc[1][jj * 4 + 2] += a1 * b.z; acc[1][jj * 4 + 3] += a1 * b.w;
        acc[2][jj * 4 + 0] += a2 * b.x; acc[2][jj * 4 + 1] += a2 * b.y;
        acc[2][jj * 4 + 2] += a2 * b.z; acc[2][jj * 4 + 3] += a2 * b.w;
        acc[3][jj * 4 + 0] += a3 * b.x; acc[3][jj * 4 + 1] += a3 * b.y;
        acc[3][jj * 4 + 2] += a3 * b.z; acc[3][jj * 4 + 3] += a3 * b.w;
      }
    }
    __syncthreads();
  }

#pragma unroll
  for (int i = 0; i < 4; ++i) {
    const int row = brow + rg * 4 + i;
#pragma unroll
    for (int jj = 0; jj < 4; ++jj) {
      const int c0 = cg * 4 + jj * 128;
      float4 o;
      o.x = acc[i][jj * 4 + 0] + bias[c0 + 0];
      o.y = acc[i][jj * 4 + 1] + bias[c0 + 1];
      o.z = acc[i][jj * 4 + 2] + bias[c0 + 2];
      o.w = acc[i][jj * 4 + 3] + bias[c0 + 3];
      *(float4*)&C[(size_t)row * 512 + c0] = o;
    }
  }
}

// ---------------------------------------------------------------------------
// DPP wave64 sum-reduce helper (r14 EXACT, hardware-proven).
// ---------------------------------------------------------------------------
__device__ static inline float dpp_add_step(float v, const int ctrl) {
  int perm;
  switch (ctrl) {  // ctrl is compile-time constant at each call site
    case 0xB1:  perm = __builtin_amdgcn_update_dpp(0, __builtin_bit_cast(int, v), 0xB1,  0xF, 0xF, true); break;
    case 0x4E:  perm = __builtin_amdgcn_update_dpp(0, __builtin_bit_cast(int, v), 0x4E,  0xF, 0xF, true); break;
    case 0x141: perm = __builtin_amdgcn_update_dpp(0, __builtin_bit_cast(int, v), 0x141, 0xF, 0xF, true); break;
    case 0x140: perm = __builtin_amdgcn_update_dpp(0, __builtin_bit_cast(int, v), 0x140, 0xF, 0xF, true); break;
    case 0x142: perm = __builtin_amdgcn_update_dpp(0, __builtin_bit_cast(int, v), 0x142, 0xF, 0xF, true); break;
    default:    perm = __builtin_amdgcn_update_dpp(0, __builtin_bit_cast(int, v), 0x143, 0xF, 0xF, true); break;
  }
  return v + __builtin_bit_cast(float, perm);
}

// ---------------------------------------------------------------------------
// Scan (r14 structure; ONE change: within-lane 8-term sums are pairwise TREES
// (3 dependent levels) instead of 8 sequential adds — s2's squares computed
// independently first. Shortens the serial critical path of each of the 1024
// steps. Depth-8 prefetch ring, DPP reduce, relu6, in-place safe.
// ---------------------------------------------------------------------------
__global__ __launch_bounds__(64) void scan_ln_relu6(
    const float* lin, const float* __restrict__ rec,
    const float* __restrict__ gam, const float* __restrict__ bet,
    float* y, float* __restrict__ hlast) {
  const int b = blockIdx.x;
  const int lane = threadIdx.x;
  const int e0 = lane * 8;

  float rf[8], gf[8], bp[8], h[8];
#pragma unroll
  for (int i = 0; i < 8; ++i) {
    rf[i] = rec[e0 + i];
    gf[i] = gam[e0 + i];
    bp[i] = bet[e0 + i];
    h[i] = 0.0f;
  }

  const size_t BH = (size_t)B_DIM * H_DIM;
  const size_t base = (size_t)b * H_DIM + e0;

  float4 pa[8], pb[8];  // prefetch ring: row s0+k held in pa[k]/pb[k]
#pragma unroll
  for (int k = 0; k < 8; ++k) {
    pa[k] = *(const float4*)&lin[base + (size_t)k * BH];
    pb[k] = *(const float4*)&lin[base + (size_t)k * BH + 4];
  }

  for (int s0 = 0; s0 < S_LEN; s0 += 8) {
#pragma unroll
    for (int k = 0; k < 8; ++k) {   // k compile-time after unroll
      const int s = s0 + k;
      float hv[8];
      hv[0] = pa[k].x + rf[0] * h[0]; hv[1] = pa[k].y + rf[1] * h[1];
      hv[2] = pa[k].z + rf[2] * h[2]; hv[3] = pa[k].w + rf[3] * h[3];
      hv[4] = pb[k].x + rf[4] * h[4]; hv[5] = pb[k].y + rf[5] * h[5];
      hv[6] = pb[k].z + rf[6] * h[6]; hv[7] = pb[k].w + rf[7] * h[7];
      if (s + 8 < S_LEN) {  // issue prefetch for s+8 (consumed 8 steps later)
        pa[k] = *(const float4*)&lin[base + (size_t)(s + 8) * BH];
        pb[k] = *(const float4*)&lin[base + (size_t)(s + 8) * BH + 4];
      }
      // --- within-lane sums as pairwise trees (3 dependent levels) ---
      float sq[8];
#pragma unroll
      for (int i = 0; i < 8; ++i) sq[i] = hv[i] * hv[i];  // independent muls
      float s1 = ((hv[0] + hv[1]) + (hv[2] + hv[3])) +
                 ((hv[4] + hv[5]) + (hv[6] + hv[7]));
      float s2 = ((sq[0] + sq[1]) + (sq[2] + sq[3])) +
                 ((sq[4] + sq[5]) + (sq[6] + sq[7]));
      // --- interleaved DPP butterfly: full 64-lane sums of s1, s2 ---
      s1 = dpp_add_step(s1, 0xB1);  s2 = dpp_add_step(s2, 0xB1);   // quad xor1
      s1 = dpp_add_step(s1, 0x4E);  s2 = dpp_add_step(s2, 0x4E);   // quad xor2
      s1 = dpp_add_step(s1, 0x141); s2 = dpp_add_step(s2, 0x141);  // half_mirror
      s1 = dpp_add_step(s1, 0x140); s2 = dpp_add_step(s2, 0x140);  // row_mirror
      s1 = dpp_add_step(s1, 0x142); s2 = dpp_add_step(s2, 0x142);  // bcast15
      s1 = dpp_add_step(s1, 0x143); s2 = dpp_add_step(s2, 0x143);  // bcast31
      const float S1 = __builtin_bit_cast(float,
          __builtin_amdgcn_readlane(__builtin_bit_cast(int, s1), 63));
      const float S2 = __builtin_bit_cast(float,
          __builtin_amdgcn_readlane(__builtin_bit_cast(int, s2), 63));
      const float mu = S1 * (1.0f / 512.0f);
      const float var = S2 * (1.0f / 512.0f) - mu * mu;  // biased variance
      const float rs = rsqrtf(var + 1e-6f);
      float4 o0, o1;
      float v;
      v = (hv[0] - mu) * rs * gf[0] + bp[0]; v = fminf(fmaxf(v, 0.0f), 6.0f); h[0] = v; o0.x = v;
      v = (hv[1] - mu) * rs * gf[1] + bp[1]; v = fminf(fmaxf(v, 0.0f), 6.0f); h[1] = v; o0.y = v;
      v = (hv[2] - mu) * rs * gf[2] + bp[2]; v = fminf(fmaxf(v, 0.0f), 6.0f); h[2] = v; o0.z = v;
      v = (hv[3] - mu) * rs * gf[3] + bp[3]; v = fminf(fmaxf(v, 0.0f), 6.0f); h[3] = v; o0.w = v;
      v = (hv[4] - mu) * rs * gf[4] + bp[4]; v = fminf(fmaxf(v, 0.0f), 6.0f); h[4] = v; o1.x = v;
      v = (hv[5] - mu) * rs * gf[5] + bp[5]; v = fminf(fmaxf(v, 0.0f), 6.0f); h[5] = v; o1.y = v;
      v = (hv[6] - mu) * rs * gf[6] + bp[6]; v = fminf(fmaxf(v, 0.0f), 6.0f); h[6] = v; o1.z = v;
      v = (hv[7] - mu) * rs * gf[7] + bp[7]; v = fminf(fmaxf(v, 0.0f), 6.0f); h[7] = v; o1.w = v;
      float* yp = y + base + (size_t)s * BH;
      *(float4*)yp = o0;
      *(float4*)(yp + 4) = o1;
    }
  }

  float* hp = hlast + b * 1024 + e0;
  float4 h0; h0.x = h[0]; h0.y = h[1]; h0.z = h[2]; h0.w = h[3];
  float4 h1; h1.x = h[4]; h1.y = h[5]; h1.z = h[6]; h1.w = h[7];
  *(float4*)hp = h0;
  *(float4*)(hp + 4) = h1;
}

extern "C" void kernel_launch(void* const* d_in, const int* in_sizes, int n_in,
                              void* d_out, int out_size, void* d_ws, size_t ws_size,
                              hipStream_t stream) {
  const float* x   = (const float*)d_in[0];
  const float* W0  = (const float*)d_in[1];
  const float* b0  = (const float*)d_in[2];
  const float* r0  = (const float*)d_in[3];
  const float* g0  = (const float*)d_in[4];
  const float* be0 = (const float*)d_in[5];
  const float* W1  = (const float*)d_in[6];
  const float* b1  = (const float*)d_in[7];
  const float* r1  = (const float*)d_in[8];
  const float* g1  = (const float*)d_in[9];
  const float* be1 = (const float*)d_in[10];

  float* out = (float*)d_out;
  float* R   = out;              // y-region: lin0 -> y0 -> lin1 -> y, in place
  float* hl0 = out + Y_SZ;       // hiddens flat: out[Y_SZ + b*1024 + l*512 + h]
  float* hl1 = out + Y_SZ + 512;
  (void)d_ws; (void)ws_size; (void)in_sizes; (void)n_in; (void)out_size;

  // layer 0
  gemm_valu<<<1024, 512, 0, stream>>>(x, W0, b0, R);
  scan_ln_relu6<<<64, 64, 0, stream>>>(R, r0, g0, be0, R, hl0);
  // layer 1 (reads y0 from R, writes lin1 over R; in-place-safe by design)
  gemm_valu<<<1024, 512, 0, stream>>>(R, W1, b1, R);
  scan_ln_relu6<<<64, 64, 0, stream>>>(R, r1, g1, be1, R, hl1);
}

// Round 22
// 1339.606 us; speedup vs baseline: 11.8110x; 1.0329x over previous
//
#include <hip/hip_runtime.h>

#define S_LEN 1024
#define B_DIM 64
#define H_DIM 512
#define Y_SZ ((size_t)S_LEN * B_DIM * H_DIM)   // 33,554,432 elements

// ---------------------------------------------------------------------------
// GEMM (r13 EXACT, hardware-proven 494 µs, 64 VGPR @ 39% occ — saturates the
// LDS pipe at its 1139 cyc/wave-kt floor; every variant regressed:
// r12 68VGPR=570, r17 confl=606, r18 8x8=565, r19 globalA=655, r20 pin=8300).
// Block owns 64 rows exclusively; all C stores after the last staging
// barrier -> in-place safe (C may alias A).
// ---------------------------------------------------------------------------
__global__ __launch_bounds__(512) void gemm_valu(
    const float* A, const float* __restrict__ W,
    const float* __restrict__ bias, float* C) {
  __shared__ float Bl[16][512];  // [k][n], staged transposed
  __shared__ float Al[64][16];   // [r][k]

  const int tid = threadIdx.x;
  const int rg = tid >> 5;   // 0..15 (4 rows each)
  const int cg = tid & 31;   // 0..31 (16 cols: cg*4 + jj*128)
  const int brow = blockIdx.x * 64;

  float acc[4][16];
#pragma unroll
  for (int i = 0; i < 4; ++i)
#pragma unroll
    for (int j = 0; j < 16; ++j) acc[i][j] = 0.0f;

  for (int kt = 0; kt < 32; ++kt) {
    {
      const float* wp = W + (size_t)tid * 512 + kt * 16;
      float4 w0 = *(const float4*)(wp + 0);
      float4 w1 = *(const float4*)(wp + 4);
      float4 w2 = *(const float4*)(wp + 8);
      float4 w3 = *(const float4*)(wp + 12);
      Bl[0][tid] = w0.x;  Bl[1][tid] = w0.y;  Bl[2][tid] = w0.z;  Bl[3][tid] = w0.w;
      Bl[4][tid] = w1.x;  Bl[5][tid] = w1.y;  Bl[6][tid] = w1.z;  Bl[7][tid] = w1.w;
      Bl[8][tid] = w2.x;  Bl[9][tid] = w2.y;  Bl[10][tid] = w2.z; Bl[11][tid] = w2.w;
      Bl[12][tid] = w3.x; Bl[13][tid] = w3.y; Bl[14][tid] = w3.z; Bl[15][tid] = w3.w;
    }
    {
      const int r = tid >> 3, kk = (tid & 7) * 2;
      const float* ap = A + (size_t)(brow + r) * 512 + kt * 16 + kk;
      Al[r][kk] = ap[0];
      Al[r][kk + 1] = ap[1];
    }
    __syncthreads();
#pragma unroll
    for (int k = 0; k < 16; ++k) {
      const float a0 = Al[rg * 4 + 0][k];
      const float a1 = Al[rg * 4 + 1][k];
      const float a2 = Al[rg * 4 + 2][k];
      const float a3 = Al[rg * 4 + 3][k];
#pragma unroll
      for (int jj = 0; jj < 4; ++jj) {
        float4 b = *(const float4*)&Bl[k][cg * 4 + jj * 128];
        acc[0][jj * 4 + 0] += a0 * b.x; acc[0][jj * 4 + 1] += a0 * b.y;
        acc[0][jj * 4 + 2] += a0 * b.z; acc[0][jj * 4 + 3] += a0 * b.w;
        acc[1][jj * 4 + 0] += a1 * b.x; acc[1][jj * 4 + 1] += a1 * b.y;
        acc[1][jj * 4 + 2] += a1 * b.z; acc[1][jj * 4 + 3] += a1 * b.w;
        acc[2][jj * 4 + 0] += a2 * b.x; acc[2][jj * 4 + 1] += a2 * b.y;
        acc[2][jj * 4 + 2] += a2 * b.z; acc[2][jj * 4 + 3] += a2 * b.w;
        acc[3][jj * 4 + 0] += a3 * b.x; acc[3][jj * 4 + 1] += a3 * b.y;
        acc[3][jj * 4 + 2] += a3 * b.z; acc[3][jj * 4 + 3] += a3 * b.w;
      }
    }
    __syncthreads();
  }

#pragma unroll
  for (int i = 0; i < 4; ++i) {
    const int row = brow + rg * 4 + i;
#pragma unroll
    for (int jj = 0; jj < 4; ++jj) {
      const int c0 = cg * 4 + jj * 128;
      float4 o;
      o.x = acc[i][jj * 4 + 0] + bias[c0 + 0];
      o.y = acc[i][jj * 4 + 1] + bias[c0 + 1];
      o.z = acc[i][jj * 4 + 2] + bias[c0 + 2];
      o.w = acc[i][jj * 4 + 3] + bias[c0 + 3];
      *(float4*)&C[(size_t)row * 512 + c0] = o;
    }
  }
}

// ---------------------------------------------------------------------------
// DPP wave64 sum-reduce helper (r14 EXACT, hardware-proven).
// ---------------------------------------------------------------------------
__device__ static inline float dpp_add_step(float v, const int ctrl) {
  int perm;
  switch (ctrl) {  // ctrl is compile-time constant at each call site
    case 0xB1:  perm = __builtin_amdgcn_update_dpp(0, __builtin_bit_cast(int, v), 0xB1,  0xF, 0xF, true); break;
    case 0x4E:  perm = __builtin_amdgcn_update_dpp(0, __builtin_bit_cast(int, v), 0x4E,  0xF, 0xF, true); break;
    case 0x141: perm = __builtin_amdgcn_update_dpp(0, __builtin_bit_cast(int, v), 0x141, 0xF, 0xF, true); break;
    case 0x140: perm = __builtin_amdgcn_update_dpp(0, __builtin_bit_cast(int, v), 0x140, 0xF, 0xF, true); break;
    case 0x142: perm = __builtin_amdgcn_update_dpp(0, __builtin_bit_cast(int, v), 0x142, 0xF, 0xF, true); break;
    default:    perm = __builtin_amdgcn_update_dpp(0, __builtin_bit_cast(int, v), 0x143, 0xF, 0xF, true); break;
  }
  return v + __builtin_bit_cast(float, perm);
}

// ---------------------------------------------------------------------------
// Scan (r14 EXACT, hardware-proven ~174 µs): depth-8 prefetch ring, one wave
// per batch row, sequential within-lane fmac sums (r21's pairwise tree
// REGRESSED to 199 µs — 15 instrs vs 8 fmac, chain wasn't binding),
// DPP reduction, relu6, in-place safe.
// ---------------------------------------------------------------------------
__global__ __launch_bounds__(64) void scan_ln_relu6(
    const float* lin, const float* __restrict__ rec,
    const float* __restrict__ gam, const float* __restrict__ bet,
    float* y, float* __restrict__ hlast) {
  const int b = blockIdx.x;
  const int lane = threadIdx.x;
  const int e0 = lane * 8;

  float rf[8], gf[8], bp[8], h[8];
#pragma unroll
  for (int i = 0; i < 8; ++i) {
    rf[i] = rec[e0 + i];
    gf[i] = gam[e0 + i];
    bp[i] = bet[e0 + i];
    h[i] = 0.0f;
  }

  const size_t BH = (size_t)B_DIM * H_DIM;
  const size_t base = (size_t)b * H_DIM + e0;

  float4 pa[8], pb[8];  // prefetch ring: row s0+k held in pa[k]/pb[k]
#pragma unroll
  for (int k = 0; k < 8; ++k) {
    pa[k] = *(const float4*)&lin[base + (size_t)k * BH];
    pb[k] = *(const float4*)&lin[base + (size_t)k * BH + 4];
  }

  for (int s0 = 0; s0 < S_LEN; s0 += 8) {
#pragma unroll
    for (int k = 0; k < 8; ++k) {   // k compile-time after unroll
      const int s = s0 + k;
      float hv[8];
      hv[0] = pa[k].x + rf[0] * h[0]; hv[1] = pa[k].y + rf[1] * h[1];
      hv[2] = pa[k].z + rf[2] * h[2]; hv[3] = pa[k].w + rf[3] * h[3];
      hv[4] = pb[k].x + rf[4] * h[4]; hv[5] = pb[k].y + rf[5] * h[5];
      hv[6] = pb[k].z + rf[6] * h[6]; hv[7] = pb[k].w + rf[7] * h[7];
      if (s + 8 < S_LEN) {  // issue prefetch for s+8 (consumed 8 steps later)
        pa[k] = *(const float4*)&lin[base + (size_t)(s + 8) * BH];
        pb[k] = *(const float4*)&lin[base + (size_t)(s + 8) * BH + 4];
      }
      float s1 = 0.0f, s2 = 0.0f;
#pragma unroll
      for (int i = 0; i < 8; ++i) {
        s1 += hv[i];
        s2 += hv[i] * hv[i];
      }
      // --- interleaved DPP butterfly: full 64-lane sums of s1, s2 ---
      s1 = dpp_add_step(s1, 0xB1);  s2 = dpp_add_step(s2, 0xB1);   // quad xor1
      s1 = dpp_add_step(s1, 0x4E);  s2 = dpp_add_step(s2, 0x4E);   // quad xor2
      s1 = dpp_add_step(s1, 0x141); s2 = dpp_add_step(s2, 0x141);  // half_mirror
      s1 = dpp_add_step(s1, 0x140); s2 = dpp_add_step(s2, 0x140);  // row_mirror
      s1 = dpp_add_step(s1, 0x142); s2 = dpp_add_step(s2, 0x142);  // bcast15
      s1 = dpp_add_step(s1, 0x143); s2 = dpp_add_step(s2, 0x143);  // bcast31
      const float S1 = __builtin_bit_cast(float,
          __builtin_amdgcn_readlane(__builtin_bit_cast(int, s1), 63));
      const float S2 = __builtin_bit_cast(float,
          __builtin_amdgcn_readlane(__builtin_bit_cast(int, s2), 63));
      const float mu = S1 * (1.0f / 512.0f);
      const float var = S2 * (1.0f / 512.0f) - mu * mu;  // biased variance
      const float rs = rsqrtf(var + 1e-6f);
      float4 o0, o1;
      float v;
      v = (hv[0] - mu) * rs * gf[0] + bp[0]; v = fminf(fmaxf(v, 0.0f), 6.0f); h[0] = v; o0.x = v;
      v = (hv[1] - mu) * rs * gf[1] + bp[1]; v = fminf(fmaxf(v, 0.0f), 6.0f); h[1] = v; o0.y = v;
      v = (hv[2] - mu) * rs * gf[2] + bp[2]; v = fminf(fmaxf(v, 0.0f), 6.0f); h[2] = v; o0.z = v;
      v = (hv[3] - mu) * rs * gf[3] + bp[3]; v = fminf(fmaxf(v, 0.0f), 6.0f); h[3] = v; o0.w = v;
      v = (hv[4] - mu) * rs * gf[4] + bp[4]; v = fminf(fmaxf(v, 0.0f), 6.0f); h[4] = v; o1.x = v;
      v = (hv[5] - mu) * rs * gf[5] + bp[5]; v = fminf(fmaxf(v, 0.0f), 6.0f); h[5] = v; o1.y = v;
      v = (hv[6] - mu) * rs * gf[6] + bp[6]; v = fminf(fmaxf(v, 0.0f), 6.0f); h[6] = v; o1.z = v;
      v = (hv[7] - mu) * rs * gf[7] + bp[7]; v = fminf(fmaxf(v, 0.0f), 6.0f); h[7] = v; o1.w = v;
      float* yp = y + base + (size_t)s * BH;
      *(float4*)yp = o0;
      *(float4*)(yp + 4) = o1;
    }
  }

  float* hp = hlast + b * 1024 + e0;
  float4 h0; h0.x = h[0]; h0.y = h[1]; h0.z = h[2]; h0.w = h[3];
  float4 h1; h1.x = h[4]; h1.y = h[5]; h1.z = h[6]; h1.w = h[7];
  *(float4*)hp = h0;
  *(float4*)(hp + 4) = h1;
}

extern "C" void kernel_launch(void* const* d_in, const int* in_sizes, int n_in,
                              void* d_out, int out_size, void* d_ws, size_t ws_size,
                              hipStream_t stream) {
  const float* x   = (const float*)d_in[0];
  const float* W0  = (const float*)d_in[1];
  const float* b0  = (const float*)d_in[2];
  const float* r0  = (const float*)d_in[3];
  const float* g0  = (const float*)d_in[4];
  const float* be0 = (const float*)d_in[5];
  const float* W1  = (const float*)d_in[6];
  const float* b1  = (const float*)d_in[7];
  const float* r1  = (const float*)d_in[8];
  const float* g1  = (const float*)d_in[9];
  const float* be1 = (const float*)d_in[10];

  float* out = (float*)d_out;
  float* R   = out;              // y-region: lin0 -> y0 -> lin1 -> y, in place
  float* hl0 = out + Y_SZ;       // hiddens flat: out[Y_SZ + b*1024 + l*512 + h]
  float* hl1 = out + Y_SZ + 512;
  (void)d_ws; (void)ws_size; (void)in_sizes; (void)n_in; (void)out_size;

  // layer 0
  gemm_valu<<<1024, 512, 0, stream>>>(x, W0, b0, R);
  scan_ln_relu6<<<64, 64, 0, stream>>>(R, r0, g0, be0, R, hl0);
  // layer 1 (reads y0 from R, writes lin1 over R; in-place-safe by design)
  gemm_valu<<<1024, 512, 0, stream>>>(R, W1, b1, R);
  scan_ln_relu6<<<64, 64, 0, stream>>>(R, r1, g1, be1, R, hl1);
}